// Round 14
// baseline (214.355 us; speedup 1.0000x reference)
//
#include <hip/hip_runtime.h>
#include <hip/hip_fp16.h>

#define NNODES 50000
#define EORIG  1600000
#define ETOT   (EORIG + NNODES)
#define NEG 0.2f
#define BSH 7
#define NBUCK ((NNODES + 127) >> BSH)   // 391
#define BCAP 5120                        // padded bucket capacity
#define NRT (NNODES / 16)               // 3125 row-tiles
#define EPB 4096
#define NBE ((ETOT + EPB - 1) / EPB)    // 403
#define LOG2E 1.44269504f

typedef _Float16 v2h __attribute__((ext_vector_type(2)));
typedef _Float16 v8h __attribute__((ext_vector_type(8)));
typedef float    v4f __attribute__((ext_vector_type(4)));

__device__ __forceinline__ float hdot2v(v2h a, v2h b, float c) {
#if __has_builtin(__builtin_amdgcn_fdot2)
    return __builtin_amdgcn_fdot2(a, b, c, false);
#else
    return c + (float)a.x * (float)b.x + (float)a.y * (float)b.y;
#endif
}

__device__ __forceinline__ float fexp2(float t) {
#if __has_builtin(__builtin_amdgcn_exp2f)
    return __builtin_amdgcn_exp2f(t);
#else
    return exp2f(t);
#endif
}

// ---------------------------------------------------------------------------
// Merged prep: blocks [0,NBE) partition edges into padded dst-buckets;
// blocks [NBE, NBE+192) pack weights to fp16 transposed.
// bcur must be zeroed beforehand (hipMemsetAsync).
// ---------------------------------------------------------------------------
__global__ __launch_bounds__(256) void prep_kernel(
    const int* __restrict__ src, const int* __restrict__ dst,
    int* __restrict__ bcur, unsigned int* __restrict__ pairs,
    const float* __restrict__ Wl, const float* __restrict__ Wr,
    const float* __restrict__ Wlmu, const float* __restrict__ Wllv,
    const float* __restrict__ Wrmu, const float* __restrict__ Wrlv,
    __half* __restrict__ WT, __half* __restrict__ WT2)
{
    if (blockIdx.x >= NBE) {
        int id = (blockIdx.x - NBE) * 256 + threadIdx.x;
        if (id < 32768) {
            int k = id >> 8, c = id & 255;
            float v = (c < 128) ? Wl[k * 128 + c] : Wr[k * 128 + (c - 128)];
            WT[c * 128 + k] = __float2half(v);
        } else if (id < 49152) {
            int loc = id - 32768;
            int k = loc >> 7, c = loc & 127;
            int sel = c >> 5, cc = c & 31;
            const float* W = sel == 0 ? Wlmu : sel == 1 ? Wllv : sel == 2 ? Wrmu : Wrlv;
            WT2[c * 128 + k] = __float2half(W[k * 32 + cc]);
        }
        return;
    }

    __shared__ int cnt[NBUCK];
    __shared__ int gbase[NBUCK];
    const int e0 = blockIdx.x * EPB;

    for (int i = threadIdx.x; i < NBUCK; i += 256) cnt[i] = 0;
    __syncthreads();

    for (int i = threadIdx.x; i < EPB; i += 256) {
        int e = e0 + i;
        if (e >= ETOT) break;
        int d = (e < EORIG) ? dst[e] : e - EORIG;
        atomicAdd(&cnt[d >> BSH], 1);
    }
    __syncthreads();

    for (int b = threadIdx.x; b < NBUCK; b += 256) {
        int c = cnt[b];
        gbase[b] = c ? (b * BCAP + atomicAdd(&bcur[b], c)) : 0;
        cnt[b] = 0;
    }
    __syncthreads();

    for (int i = threadIdx.x; i < EPB; i += 256) {
        int e = e0 + i;
        if (e >= ETOT) break;
        int s, d;
        if (e < EORIG) { s = src[e]; d = dst[e]; }
        else           { s = d = e - EORIG; }
        int b = d >> BSH;
        int slot = atomicAdd(&cnt[b], 1);
        pairs[gbase[b] + slot] = (unsigned)s | ((unsigned)(d & 127) << 16);
    }
}

// ---------------------------------------------------------------------------
// csrfill: per-bucket local hist+scan -> begend int2 + ushort csr (simple).
// ---------------------------------------------------------------------------
__global__ __launch_bounds__(256) void csrfill_kernel(
    const unsigned int* __restrict__ pairs, const int* __restrict__ bcur,
    int2* __restrict__ begend, unsigned short* __restrict__ csr)
{
    __shared__ int cnt[128];
    __shared__ int lofs[128];
    __shared__ int scnt[128];
    const int b = blockIdx.x, n0 = b << BSH;
    const int nn = min(128, NNODES - n0);
    const int pbase = b * BCAP;
    const int pend = pbase + bcur[b];
    const int t = threadIdx.x;

    if (t < 128) { cnt[t] = 0; scnt[t] = 0; }
    __syncthreads();
    for (int i = pbase + t; i < pend; i += 256)
        atomicAdd(&cnt[pairs[i] >> 16], 1);
    __syncthreads();

    int myc = (t < 128) ? cnt[t] : 0;
    if (t < 128) lofs[t] = myc;
    __syncthreads();
    for (int off = 1; off < 128; off <<= 1) {
        int v = (t < 128 && t >= off) ? lofs[t - off] : 0;
        __syncthreads();
        if (t < 128) lofs[t] += v;
        __syncthreads();
    }
    if (t < 128) lofs[t] = pbase + lofs[t] - myc;   // exclusive + bucket base
    __syncthreads();

    if (t < nn) begend[n0 + t] = make_int2(lofs[t], lofs[t] + myc);

    for (int i = pbase + t; i < pend; i += 256) {
        unsigned pr = pairs[i];
        int l = pr >> 16;
        int slot = atomicAdd(&scnt[l], 1);
        csr[lofs[l] + slot] = (unsigned short)(pr & 0xFFFFu);
    }
}

// ---------------------------------------------------------------------------
// Layer-1 dual linear via MFMA (16x16x32 f16).
// ---------------------------------------------------------------------------
__global__ __launch_bounds__(256) void lin1_kernel(
    const float* __restrict__ x, const __half* __restrict__ WT,
    const float* __restrict__ bl, const float* __restrict__ br,
    __half* __restrict__ xl16, __half* __restrict__ xr16)
{
    int rt = (blockIdx.x * 256 + threadIdx.x) >> 6;
    if (rt >= NRT) return;
    int l  = threadIdx.x & 63;
    int lr = l & 15, lg = l >> 4;
    int row = rt * 16 + lr;

    v8h a[4];
    const float4* xrow = reinterpret_cast<const float4*>(x + (size_t)row * 128);
    #pragma unroll
    for (int ks = 0; ks < 4; ++ks) {
        float4 f0 = xrow[ks * 8 + lg * 2];
        float4 f1 = xrow[ks * 8 + lg * 2 + 1];
        v8h t;
        t[0]=(_Float16)f0.x; t[1]=(_Float16)f0.y; t[2]=(_Float16)f0.z; t[3]=(_Float16)f0.w;
        t[4]=(_Float16)f1.x; t[5]=(_Float16)f1.y; t[6]=(_Float16)f1.z; t[7]=(_Float16)f1.w;
        a[ks] = t;
    }

    const uint4* wt4 = reinterpret_cast<const uint4*>(WT);
    #pragma unroll 4
    for (int ct = 0; ct < 16; ++ct) {
        int c = ct * 16 + lr;
        v4f acc = {0.f, 0.f, 0.f, 0.f};
        #pragma unroll
        for (int ks = 0; ks < 4; ++ks) {
            union { uint4 u; v8h h; } B;
            B.u = wt4[(size_t)c * 16 + ks * 4 + lg];
            acc = __builtin_amdgcn_mfma_f32_16x16x32_f16(a[ks], B.h, acc, 0, 0, 0);
        }
        float bb = (c < 128) ? bl[c] : br[c - 128];
        #pragma unroll
        for (int j = 0; j < 4; ++j) {
            int orow = rt * 16 + lg * 4 + j;
            __half hv = __float2half(acc[j] + bb);
            if (c < 128) xl16[(size_t)orow * 128 + c] = hv;
            else         xr16[(size_t)orow * 128 + (c - 128)] = hv;
        }
    }
}

// ---------------------------------------------------------------------------
// Layer-2 quad linear via MFMA.
// ---------------------------------------------------------------------------
__global__ __launch_bounds__(256) void lin2_kernel(
    const __half* __restrict__ h16, const __half* __restrict__ WT2,
    const float* __restrict__ blmu, const float* __restrict__ bllv,
    const float* __restrict__ brmu, const float* __restrict__ brlv,
    __half* __restrict__ xi16, __half* __restrict__ xrI16)
{
    int rt = (blockIdx.x * 256 + threadIdx.x) >> 6;
    if (rt >= NRT) return;
    int l  = threadIdx.x & 63;
    int lr = l & 15, lg = l >> 4;
    int row = rt * 16 + lr;

    v8h a[4];
    const uint4* hrow = reinterpret_cast<const uint4*>(h16 + (size_t)row * 128);
    #pragma unroll
    for (int ks = 0; ks < 4; ++ks) {
        union { uint4 u; v8h h; } A;
        A.u = hrow[ks * 4 + lg];
        a[ks] = A.h;
    }

    const uint4* wt4 = reinterpret_cast<const uint4*>(WT2);
    #pragma unroll 4
    for (int ct = 0; ct < 8; ++ct) {
        int c = ct * 16 + lr;
        v4f acc = {0.f, 0.f, 0.f, 0.f};
        #pragma unroll
        for (int ks = 0; ks < 4; ++ks) {
            union { uint4 u; v8h h; } B;
            B.u = wt4[(size_t)c * 16 + ks * 4 + lg];
            acc = __builtin_amdgcn_mfma_f32_16x16x32_f16(a[ks], B.h, acc, 0, 0, 0);
        }
        int sel = c >> 5, cc = c & 31;
        const float* bp = sel == 0 ? blmu : sel == 1 ? bllv : sel == 2 ? brmu : brlv;
        float bb = bp[cc];
        #pragma unroll
        for (int j = 0; j < 4; ++j) {
            int orow = rt * 16 + lg * 4 + j;
            __half hv = __float2half(acc[j] + bb);
            if (c < 64) xi16 [(size_t)orow * 64 + c]      = hv;
            else        xrI16[(size_t)orow * 64 + (c-64)] = hv;
        }
    }
}

// ---------------------------------------------------------------------------
// Layer-1 gather, DUAL-NODE: one wave handles nodes 2w and 2w+1 with
// independent pipelines (4 row-load instrs in flight -> 2x memory parallelism).
// Per node: 8 edges/iter (2 per quarter), depth-2 pipeline.
// ---------------------------------------------------------------------------
__global__ __launch_bounds__(256) void gat_gather1(
    const __half* __restrict__ xl16, const __half* __restrict__ xr16,
    const float* __restrict__ att, const float* __restrict__ bias,
    const int2* __restrict__ begend, const unsigned short* __restrict__ csr,
    __half* __restrict__ h16)
{
    int w = (blockIdx.x * 256 + threadIdx.x) >> 6;
    if (w >= NNODES / 2) return;
    int d0 = w * 2, d1 = d0 + 1;
    int lane = threadIdx.x & 63;
    int quarter = lane >> 4;
    int q = lane & 15;
    int qo = quarter * 2;

    v2h ath[4];
    {
        const float4* t4 = reinterpret_cast<const float4*>(att) + q * 2;
        float4 a = t4[0], b = t4[1];
        ath[0] = (v2h){(_Float16)(a.x*LOG2E), (_Float16)(a.y*LOG2E)};
        ath[1] = (v2h){(_Float16)(a.z*LOG2E), (_Float16)(a.w*LOG2E)};
        ath[2] = (v2h){(_Float16)(b.x*LOG2E), (_Float16)(b.y*LOG2E)};
        ath[3] = (v2h){(_Float16)(b.z*LOG2E), (_Float16)(b.w*LOG2E)};
    }
    v2h xrh0[4], xrh1[4];
    {
        union { uint4 u; v2h v[4]; } R;
        R.u = reinterpret_cast<const uint4*>(xr16)[(size_t)d0 * 16 + q];
        #pragma unroll
        for (int j = 0; j < 4; ++j) xrh0[j] = R.v[j];
        R.u = reinterpret_cast<const uint4*>(xr16)[(size_t)d1 * 16 + q];
        #pragma unroll
        for (int j = 0; j < 4; ++j) xrh1[j] = R.v[j];
    }
    const v2h neg2 = (v2h){(_Float16)NEG, (_Float16)NEG};

    int2 be0 = begend[d0], be1 = begend[d1];
    int beg0 = be0.x, end0 = be0.y;
    int beg1 = be1.x, end1 = be1.y;
    int nI = max((end0 - beg0 + 7) >> 3, (end1 - beg1 + 7) >> 3);
    const uint4* xlu = reinterpret_cast<const uint4*>(xl16);

    float den0 = 0.f, den1 = 0.f;
    float acc0[8] = {0,0,0,0,0,0,0,0}, acc1[8] = {0,0,0,0,0,0,0,0};

    auto computeN = [&](uint4 U, bool val, const v2h* xrh, float& den, float* acc) {
        union { uint4 u; v2h v[4]; } X; X.u = U;
        float t = 0.f;
        #pragma unroll
        for (int j = 0; j < 4; ++j) {
            v2h s = X.v[j] + xrh[j];
            v2h l = __builtin_elementwise_max(s, s * neg2);
            t = hdot2v(l, ath[j], t);
        }
        t += __shfl_xor(t, 1, 64);
        t += __shfl_xor(t, 2, 64);
        float p = val ? fexp2(t) : 0.f;
        den += p;
        #pragma unroll
        for (int j = 0; j < 4; ++j) {
            acc[2*j]   += p * (float)X.v[j].x;
            acc[2*j+1] += p * (float)X.v[j].y;
        }
    };

    int  iA0[2], iA1[2], iB0[2], iB1[2];
    bool vA0[2], vA1[2], vB0[2], vB1[2];
    uint4 rA0[2], rA1[2];

    #pragma unroll
    for (int k = 0; k < 2; ++k) {
        int s0 = beg0 + qo + k;
        vA0[k] = s0 < end0;
        iA0[k] = csr[vA0[k] ? s0 : end0 - 1];
        int s1 = beg1 + qo + k;
        vA1[k] = s1 < end1;
        iA1[k] = csr[vA1[k] ? s1 : end1 - 1];
    }
    #pragma unroll
    for (int k = 0; k < 2; ++k) {
        rA0[k] = xlu[(size_t)iA0[k] * 16 + q];
        rA1[k] = xlu[(size_t)iA1[k] * 16 + q];
    }
    #pragma unroll
    for (int k = 0; k < 2; ++k) {
        int s0 = beg0 + 8 + qo + k;
        vB0[k] = s0 < end0;
        iB0[k] = csr[vB0[k] ? s0 : end0 - 1];
        int s1 = beg1 + 8 + qo + k;
        vB1[k] = s1 < end1;
        iB1[k] = csr[vB1[k] ? s1 : end1 - 1];
    }

    for (int it = 0; it < nI; ++it) {
        int b20 = beg0 + (it + 2) * 8;
        int b21 = beg1 + (it + 2) * 8;
        int  iC0[2], iC1[2]; bool vC0[2], vC1[2];
        #pragma unroll
        for (int k = 0; k < 2; ++k) {
            int s0 = b20 + qo + k;
            vC0[k] = s0 < end0;
            iC0[k] = csr[vC0[k] ? s0 : end0 - 1];
            int s1 = b21 + qo + k;
            vC1[k] = s1 < end1;
            iC1[k] = csr[vC1[k] ? s1 : end1 - 1];
        }
        uint4 rB0[2], rB1[2];
        #pragma unroll
        for (int k = 0; k < 2; ++k) {
            rB0[k] = xlu[(size_t)iB0[k] * 16 + q];
            rB1[k] = xlu[(size_t)iB1[k] * 16 + q];
        }
        computeN(rA0[0], vA0[0], xrh0, den0, acc0);
        computeN(rA0[1], vA0[1], xrh0, den0, acc0);
        computeN(rA1[0], vA1[0], xrh1, den1, acc1);
        computeN(rA1[1], vA1[1], xrh1, den1, acc1);
        #pragma unroll
        for (int k = 0; k < 2; ++k) {
            rA0[k] = rB0[k]; vA0[k] = vB0[k];
            rA1[k] = rB1[k]; vA1[k] = vB1[k];
            iB0[k] = iC0[k]; vB0[k] = vC0[k];
            iB1[k] = iC1[k]; vB1[k] = vC1[k];
        }
    }

    den0 += __shfl_xor(den0, 16, 64); den0 += __shfl_xor(den0, 32, 64);
    den1 += __shfl_xor(den1, 16, 64); den1 += __shfl_xor(den1, 32, 64);
    #pragma unroll
    for (int j = 0; j < 8; ++j) {
        acc0[j] += __shfl_xor(acc0[j], 16, 64);
        acc0[j] += __shfl_xor(acc0[j], 32, 64);
        acc1[j] += __shfl_xor(acc1[j], 16, 64);
        acc1[j] += __shfl_xor(acc1[j], 32, 64);
    }

    if (quarter < 2) {
        const float* ac = quarter == 0 ? acc0 : acc1;
        float den = quarter == 0 ? den0 : den1;
        int d = quarter == 0 ? d0 : d1;
        float r = 1.f / den;
        const float4* bp = reinterpret_cast<const float4*>(bias) + q * 2;
        float4 ba = bp[0], bb = bp[1];
        __half hv[8];
        hv[0] = __float2half(fmaxf(ac[0]*r+ba.x, 0.f));
        hv[1] = __float2half(fmaxf(ac[1]*r+ba.y, 0.f));
        hv[2] = __float2half(fmaxf(ac[2]*r+ba.z, 0.f));
        hv[3] = __float2half(fmaxf(ac[3]*r+ba.w, 0.f));
        hv[4] = __float2half(fmaxf(ac[4]*r+bb.x, 0.f));
        hv[5] = __float2half(fmaxf(ac[5]*r+bb.y, 0.f));
        hv[6] = __float2half(fmaxf(ac[6]*r+bb.z, 0.f));
        hv[7] = __float2half(fmaxf(ac[7]*r+bb.w, 0.f));
        *reinterpret_cast<uint4*>(&h16[(size_t)d * 128 + q * 8]) =
            *reinterpret_cast<uint4*>(hv);
    }
}

// ---------------------------------------------------------------------------
// Layer-2 gather, DUAL-NODE, 8-edge granule (1 per oct), depth-2 pipeline.
// Rows are [mu|lv] interleaved 128B.
// ---------------------------------------------------------------------------
__global__ __launch_bounds__(256) void gat_gather2(
    const __half* __restrict__ xi16, const __half* __restrict__ xrI16,
    const float* __restrict__ atmu, const float* __restrict__ atlv,
    const float* __restrict__ bmu,  const float* __restrict__ blv,
    const int2* __restrict__ begend, const unsigned short* __restrict__ csr,
    float* __restrict__ out)
{
    int w = (blockIdx.x * 256 + threadIdx.x) >> 6;
    if (w >= NNODES / 2) return;
    int d0 = w * 2, d1 = d0 + 1;
    int lane = threadIdx.x & 63;
    int oct = lane >> 3;
    int r   = lane & 7;
    bool lv = r >= 4;
    int cq  = lv ? r - 4 : r;

    v2h ath[4];
    {
        const float4* t4 = reinterpret_cast<const float4*>(lv ? atlv : atmu) + cq * 2;
        float4 a = t4[0], b = t4[1];
        ath[0] = (v2h){(_Float16)(a.x*LOG2E), (_Float16)(a.y*LOG2E)};
        ath[1] = (v2h){(_Float16)(a.z*LOG2E), (_Float16)(a.w*LOG2E)};
        ath[2] = (v2h){(_Float16)(b.x*LOG2E), (_Float16)(b.y*LOG2E)};
        ath[3] = (v2h){(_Float16)(b.z*LOG2E), (_Float16)(b.w*LOG2E)};
    }
    v2h xrh0[4], xrh1[4];
    {
        union { uint4 u; v2h v[4]; } R;
        R.u = reinterpret_cast<const uint4*>(xrI16)[(size_t)d0 * 8 + r];
        #pragma unroll
        for (int j = 0; j < 4; ++j) xrh0[j] = R.v[j];
        R.u = reinterpret_cast<const uint4*>(xrI16)[(size_t)d1 * 8 + r];
        #pragma unroll
        for (int j = 0; j < 4; ++j) xrh1[j] = R.v[j];
    }
    const v2h neg2 = (v2h){(_Float16)NEG, (_Float16)NEG};

    int2 be0 = begend[d0], be1 = begend[d1];
    int beg0 = be0.x, end0 = be0.y;
    int beg1 = be1.x, end1 = be1.y;
    int nI = max((end0 - beg0 + 7) >> 3, (end1 - beg1 + 7) >> 3);
    const uint4* xiu = reinterpret_cast<const uint4*>(xi16);

    float den0 = 0.f, den1 = 0.f;
    float acc0[8] = {0,0,0,0,0,0,0,0}, acc1[8] = {0,0,0,0,0,0,0,0};

    auto computeN = [&](uint4 U, bool val, const v2h* xrh, float& den, float* acc) {
        union { uint4 u; v2h v[4]; } X; X.u = U;
        float t = 0.f;
        #pragma unroll
        for (int j = 0; j < 4; ++j) {
            v2h s = X.v[j] + xrh[j];
            v2h l = __builtin_elementwise_max(s, s * neg2);
            t = hdot2v(l, ath[j], t);
        }
        t += __shfl_xor(t, 1, 64);
        t += __shfl_xor(t, 2, 64);
        float p = val ? fexp2(t) : 0.f;
        den += p;
        #pragma unroll
        for (int j = 0; j < 4; ++j) {
            acc[2*j]   += p * (float)X.v[j].x;
            acc[2*j+1] += p * (float)X.v[j].y;
        }
    };

    int  iA0, iA1, iB0, iB1;
    bool vA0, vA1, vB0, vB1;
    uint4 rA0, rA1;

    {
        int s0 = beg0 + oct;
        vA0 = s0 < end0;
        iA0 = csr[vA0 ? s0 : end0 - 1];
        int s1 = beg1 + oct;
        vA1 = s1 < end1;
        iA1 = csr[vA1 ? s1 : end1 - 1];
        rA0 = xiu[(size_t)iA0 * 8 + r];
        rA1 = xiu[(size_t)iA1 * 8 + r];
        s0 = beg0 + 8 + oct;
        vB0 = s0 < end0;
        iB0 = csr[vB0 ? s0 : end0 - 1];
        s1 = beg1 + 8 + oct;
        vB1 = s1 < end1;
        iB1 = csr[vB1 ? s1 : end1 - 1];
    }

    for (int it = 0; it < nI; ++it) {
        int s0 = beg0 + (it + 2) * 8 + oct;
        bool vC0 = s0 < end0;
        int  iC0 = csr[vC0 ? s0 : end0 - 1];
        int s1 = beg1 + (it + 2) * 8 + oct;
        bool vC1 = s1 < end1;
        int  iC1 = csr[vC1 ? s1 : end1 - 1];
        uint4 rB0 = xiu[(size_t)iB0 * 8 + r];
        uint4 rB1 = xiu[(size_t)iB1 * 8 + r];
        computeN(rA0, vA0, xrh0, den0, acc0);
        computeN(rA1, vA1, xrh1, den1, acc1);
        rA0 = rB0; vA0 = vB0; iB0 = iC0; vB0 = vC0;
        rA1 = rB1; vA1 = vB1; iB1 = iC1; vB1 = vC1;
    }

    den0 += __shfl_xor(den0, 8, 64);
    den0 += __shfl_xor(den0, 16, 64);
    den0 += __shfl_xor(den0, 32, 64);
    den1 += __shfl_xor(den1, 8, 64);
    den1 += __shfl_xor(den1, 16, 64);
    den1 += __shfl_xor(den1, 32, 64);
    #pragma unroll
    for (int j = 0; j < 8; ++j) {
        acc0[j] += __shfl_xor(acc0[j], 8, 64);
        acc0[j] += __shfl_xor(acc0[j], 16, 64);
        acc0[j] += __shfl_xor(acc0[j], 32, 64);
        acc1[j] += __shfl_xor(acc1[j], 8, 64);
        acc1[j] += __shfl_xor(acc1[j], 16, 64);
        acc1[j] += __shfl_xor(acc1[j], 32, 64);
    }

    if (oct < 2) {
        const float* ac = oct == 0 ? acc0 : acc1;
        float den = oct == 0 ? den0 : den1;
        int d = oct == 0 ? d0 : d1;
        float rr = 1.f / den;
        const float4* bp = reinterpret_cast<const float4*>(lv ? blv : bmu) + cq * 2;
        float4 ba = bp[0], bb = bp[1];
        float4 o1 = make_float4(ac[0]*rr+ba.x, ac[1]*rr+ba.y,
                                ac[2]*rr+ba.z, ac[3]*rr+ba.w);
        float4 o2 = make_float4(ac[4]*rr+bb.x, ac[5]*rr+bb.y,
                                ac[6]*rr+bb.z, ac[7]*rr+bb.w);
        float* base_out = out + (lv ? 1600000 : 0);
        float4* op = reinterpret_cast<float4*>(base_out) + (size_t)d * 8 + cq * 2;
        op[0] = o1; op[1] = o2;
    }
}

extern "C" void kernel_launch(void* const* d_in, const int* in_sizes, int n_in,
                              void* d_out, int out_size, void* d_ws, size_t ws_size,
                              hipStream_t stream) {
    const float* x    = (const float*)d_in[0];
    const int*   ei   = (const int*)d_in[1];
    const float* Wl1  = (const float*)d_in[2];
    const float* bl1  = (const float*)d_in[3];
    const float* Wr1  = (const float*)d_in[4];
    const float* br1  = (const float*)d_in[5];
    const float* att1 = (const float*)d_in[6];
    const float* b1   = (const float*)d_in[7];
    const float* Wlmu = (const float*)d_in[8];
    const float* blmu = (const float*)d_in[9];
    const float* Wrmu = (const float*)d_in[10];
    const float* brmu = (const float*)d_in[11];
    const float* atmu = (const float*)d_in[12];
    const float* bmu  = (const float*)d_in[13];
    const float* Wllv = (const float*)d_in[14];
    const float* bllv = (const float*)d_in[15];
    const float* Wrlv = (const float*)d_in[16];
    const float* brlv = (const float*)d_in[17];
    const float* atlv = (const float*)d_in[18];
    const float* blv  = (const float*)d_in[19];

    float* out = (float*)d_out;
    float* ws  = (float*)d_ws;

    __half* xl16 = (__half*)ws;                      // 6.4M halves
    __half* xr16 = (__half*)(ws + 3200000);          // 6.4M halves
    __half* h16  = (__half*)(ws + 6400000);          // 6.4M halves
    __half* WT   = (__half*)(ws + 9600000);          // 32768 halves
    __half* WT2  = (__half*)(ws + 9620000);          // 16384 halves

    __half* xi16  = (__half*)ws;                     // aliases (dead xl16)
    __half* xrI16 = (__half*)(ws + 1600000);

    int* ip = (int*)(ws + 10000000);
    unsigned int*   pairs  = (unsigned int*)ip;               // 391*5120 = 2,001,920
    int*            bcur   = ip + 2001920;                    // 392
    int2*           begend = (int2*)(ip + 2002312);           // 50,000 int2
    unsigned short* csr    = (unsigned short*)(ip + 2102312); // 2,001,920 u16

    const int* srcp = ei;
    const int* dstp = ei + EORIG;

    // ---- CSR build + weight pack (merged; bcur zeroed first) ----
    hipMemsetAsync(bcur, 0, NBUCK * sizeof(int), stream);
    prep_kernel<<<NBE + 192, 256, 0, stream>>>(
        srcp, dstp, bcur, pairs, Wl1, Wr1, Wlmu, Wllv, Wrmu, Wrlv, WT, WT2);
    csrfill_kernel<<<NBUCK, 256, 0, stream>>>(pairs, bcur, begend, csr);

    // ---- layer 1 ----
    lin1_kernel<<<(NRT + 3) / 4, 256, 0, stream>>>(x, WT, bl1, br1, xl16, xr16);

    gat_gather1<<<(NNODES / 2 * 64 + 255) / 256, 256, 0, stream>>>(
        xl16, xr16, att1, b1, begend, csr, h16);

    // ---- layer 2 ----
    lin2_kernel<<<(NRT + 3) / 4, 256, 0, stream>>>(
        h16, WT2, blmu, bllv, brmu, brlv, xi16, xrI16);

    gat_gather2<<<(NNODES / 2 * 64 + 255) / 256, 256, 0, stream>>>(
        xi16, xrI16, atmu, atlv, bmu, blv, begend, csr, out);
}